// Round 7
// baseline (485.590 us; speedup 1.0000x reference)
//
#include <hip/hip_runtime.h>
#include <hip/hip_bf16.h>
#include <hip/hip_fp16.h>
#include <hip/hip_cooperative_groups.h>

namespace cg = cooperative_groups;

// GCN 2-layer: z = relu(A(relu(A(xW1)+b1)W2)+b2), A = D^-1/2 (Adj+I) D^-1/2
// N=50000, E=800000, D=128. Output: float32.
// CSR built in ONE cooperative kernel (2-level counting sort, LDS atomics only).

#define BK 128                      // nodes per bucket
#define PACK_ROWBITS 20             // row in bits [0,20), colLocal in [20,27)
#define NB_MAX 512

// ---- fused CSR build: hist -> scan -> scatter -> degree -> scan -> fill ----
__global__ __launch_bounds__(256) void k_csr(const int* __restrict__ row,
                                             const int* __restrict__ col,
                                             int* bcnt, int* bstart, int* gcur,
                                             unsigned* ebuf, int* srcs,
                                             int* degi, float* dinv,
                                             int* excl, int* partials,
                                             int N, int E, int NB, int chunk,
                                             int nScanBlk) {
    cg::grid_group grid = cg::this_grid();
    __shared__ int h[NB_MAX];
    __shared__ int base[NB_MAX];
    const int t = threadIdx.x;
    const int b = blockIdx.x;

    // S0: zero global counters (block b owns slot b)
    if (t == 0) { bcnt[b] = 0; gcur[b] = 0; }
    // S1a: LDS bucket histogram over strided edges
    for (int i = t; i < NB; i += 256) h[i] = 0;
    __syncthreads();
    for (int e = b * 256 + t; e < E; e += gridDim.x * 256)
        atomicAdd(&h[col[e] >> 7], 1);
    __syncthreads();
    grid.sync();                                   // all bcnt zeroed
    // S1b: flush LDS hist to global
    for (int i = t; i < NB; i += 256)
        if (h[i]) atomicAdd(&bcnt[i], h[i]);
    grid.sync();                                   // bcnt complete
    // S2: bstart[b] = sum_{i<b} bcnt[i]  (redundant per-block reduction)
    {
        int sum = 0;
        for (int i = t; i < b; i += 256) sum += bcnt[i];
        base[t] = sum; __syncthreads();
        for (int o = 128; o > 0; o >>= 1) {
            if (t < o) base[t] += base[t + o];
            __syncthreads();
        }
        if (t == 0) bstart[b] = base[0];
        if (b == 0 && t == 0) bstart[NB] = E;
    }
    grid.sync();                                   // bstart complete
    // S3: scatter packed entries; block b owns edge chunk b
    for (int i = t; i < NB; i += 256) h[i] = 0;
    __syncthreads();
    const int e0 = b * chunk;
    const int e1 = min(e0 + chunk, E);
    for (int e = e0 + t; e < e1; e += 256) atomicAdd(&h[col[e] >> 7], 1);
    __syncthreads();
    for (int i = t; i < NB; i += 256) {
        base[i] = h[i] ? atomicAdd(&gcur[i], h[i]) : 0;
        h[i] = 0;                                  // reuse as local cursor
    }
    __syncthreads();
    for (int e = e0 + t; e < e1; e += 256) {
        int c = col[e];
        int bk = c >> 7;
        int loc = atomicAdd(&h[bk], 1);
        ebuf[bstart[bk] + base[bk] + loc] =
            (unsigned)row[e] | ((unsigned)(c & (BK - 1)) << PACK_ROWBITS);
    }
    grid.sync();                                   // ebuf complete
    // S4: per-bucket node degrees + dinv (block b = bucket b)
    if (t < BK) h[t] = 0;
    __syncthreads();
    const int s = bstart[b], cnt = bstart[b + 1] - s;
    for (int i = t; i < cnt; i += 256)
        atomicAdd(&h[(ebuf[s + i] >> PACK_ROWBITS) & (BK - 1)], 1);
    __syncthreads();
    {
        int node = b * BK + t;
        if (t < BK && node < N) {
            degi[node] = h[t];
            dinv[node] = rsqrtf((float)h[t] + 1.0f);   // +1 self loop
        }
    }
    grid.sync();                                   // degi complete
    // S5: node-level local exclusive scan (block b < nScanBlk handles 256 nodes)
    if (b < nScanBlk) {
        int i = b * 256 + t;
        int v = (i < N) ? degi[i] : 0;
        h[t] = v; __syncthreads();
        for (int o = 1; o < 256; o <<= 1) {
            int x = (t >= o) ? h[t - o] : 0;
            __syncthreads();
            h[t] += x;
            __syncthreads();
        }
        if (i < N) excl[i] = h[t] - v;
        if (t == 255) partials[b] = h[255];
    }
    grid.sync();                                   // excl/partials complete
    // S6: scan partials[nScanBlk] (block 0, nScanBlk <= 256)
    if (b == 0) {
        int v = (t < nScanBlk) ? partials[t] : 0;
        h[t] = v; __syncthreads();
        for (int o = 1; o < 256; o <<= 1) {
            int x = (t >= o) ? h[t - o] : 0;
            __syncthreads();
            h[t] += x;
            __syncthreads();
        }
        if (t < nScanBlk) partials[t] = h[t] - v;  // exclusive over chunks
    }
    grid.sync();                                   // partials complete
    // S7: per-bucket node-level CSR fill (block b = bucket b)
    if (t < BK) h[t] = 0;
    __syncthreads();
    const int n0 = b * BK;
    for (int i = t; i < cnt; i += 256) {
        unsigned u = ebuf[s + i];
        int c = (u >> PACK_ROWBITS) & (BK - 1);
        int node = n0 + c;
        int loc = atomicAdd(&h[c], 1);
        srcs[excl[node] + partials[node >> 8] + loc] =
            (int)(u & ((1u << PACK_ROWBITS) - 1));
    }
}

// --- C[M,128] = A[M,128] @ W[128,128], f32 accumulate, fp16 output ---
template <typename TIN>
__global__ __launch_bounds__(256) void k_gemm(const TIN* __restrict__ A,
                                              const float* __restrict__ W,
                                              __half* __restrict__ C, int M) {
    __shared__ float Xl[128][68];
    const int t = threadIdx.x;
    const int row0 = blockIdx.x * 64;

    for (int c = t; c < 2048; c += 256) {
        int kq = c & 31, r = c >> 5;
        float4 v = make_float4(0.f, 0.f, 0.f, 0.f);
        int gr = row0 + r;
        if (gr < M) {
            if constexpr (sizeof(TIN) == 4) {
                v = ((const float4*)A)[gr * 32 + kq];
            } else {
                uint2 hp = ((const uint2*)A)[gr * 32 + kq];
                float2 a = __half22float2(*reinterpret_cast<__half2*>(&hp.x));
                float2 b = __half22float2(*reinterpret_cast<__half2*>(&hp.y));
                v = make_float4(a.x, a.y, b.x, b.y);
            }
        }
        Xl[4 * kq + 0][r] = v.x;
        Xl[4 * kq + 1][r] = v.y;
        Xl[4 * kq + 2][r] = v.z;
        Xl[4 * kq + 3][r] = v.w;
    }
    __syncthreads();

    const int cg = t & 31;
    const int rg = t >> 5;
    float acc[8][4];
#pragma unroll
    for (int i = 0; i < 8; i++)
#pragma unroll
        for (int j = 0; j < 4; j++) acc[i][j] = 0.f;

    const float4* Wv = (const float4*)W;
#pragma unroll 4
    for (int k = 0; k < 128; k++) {
        const float4 w  = Wv[(k << 5) + cg];
        const float4 xa = *(const float4*)(&Xl[k][rg << 3]);
        const float4 xb = *(const float4*)(&Xl[k][(rg << 3) + 4]);
        const float xs[8] = {xa.x, xa.y, xa.z, xa.w, xb.x, xb.y, xb.z, xb.w};
        const float ws4[4] = {w.x, w.y, w.z, w.w};
#pragma unroll
        for (int i = 0; i < 8; i++)
#pragma unroll
            for (int j = 0; j < 4; j++) acc[i][j] = fmaf(xs[i], ws4[j], acc[i][j]);
    }

#pragma unroll
    for (int i = 0; i < 8; i++) {
        int row = row0 + (rg << 3) + i;
        if (row < M) {
            __half2 p0 = __floats2half2_rn(acc[i][0], acc[i][1]);
            __half2 p1 = __floats2half2_rn(acc[i][2], acc[i][3]);
            uint2 pk;
            pk.x = *reinterpret_cast<unsigned*>(&p0);
            pk.y = *reinterpret_cast<unsigned*>(&p1);
            ((uint2*)C)[row * 32 + cg] = pk;
        }
    }
}

// --- aggregation: out = relu(di*(sum_j dj*H[j] + di*H[i]) + b), H fp16 ---
__global__ __launch_bounds__(256) void k_agg(const __half* __restrict__ H,
                                             const int* __restrict__ srcs,
                                             const int* __restrict__ excl,
                                             const int* __restrict__ partials,
                                             const int* __restrict__ degi,
                                             const float* __restrict__ dinv,
                                             const float* __restrict__ bias,
                                             float* __restrict__ outF,
                                             __half* __restrict__ outH, int n) {
    int wave = threadIdx.x >> 6, lane = threadIdx.x & 63;
    int node = blockIdx.x * 4 + wave;
    if (node >= n) return;
    int s0 = excl[node] + partials[node >> 8];
    int d = degi[node];
    float di = dinv[node];
    const __half2* Hv = (const __half2*)H;

    float2 hv = __half22float2(Hv[(size_t)node * 64 + lane]);
    float ax = di * hv.x, ay = di * hv.y;

    for (int k = 0; k < d; k += 64) {
        int take = d - k; if (take > 64) take = 64;
        int idx = (lane < take) ? srcs[s0 + k + lane] : 0;
        float djl = (lane < take) ? dinv[idx] : 0.f;
        int u = 0;
        for (; u + 8 <= take; u += 8) {
            int jj[8]; float dd[8]; float2 vv[8];
#pragma unroll
            for (int q = 0; q < 8; q++) {
                jj[q] = __shfl(idx, u + q);
                dd[q] = __shfl(djl, u + q);
            }
#pragma unroll
            for (int q = 0; q < 8; q++) vv[q] = __half22float2(Hv[(size_t)jj[q] * 64 + lane]);
#pragma unroll
            for (int q = 0; q < 8; q++) {
                ax = fmaf(dd[q], vv[q].x, ax);
                ay = fmaf(dd[q], vv[q].y, ay);
            }
        }
        for (; u < take; u++) {
            int j = __shfl(idx, u);
            float dj = __shfl(djl, u);
            float2 v = __half22float2(Hv[(size_t)j * 64 + lane]);
            ax = fmaf(dj, v.x, ax); ay = fmaf(dj, v.y, ay);
        }
    }
    float2 b2 = ((const float2*)bias)[lane];
    float ox = fmaxf(fmaf(di, ax, b2.x), 0.f);
    float oy = fmaxf(fmaf(di, ay, b2.y), 0.f);
    if (outF) {
        ((float2*)outF)[(size_t)node * 64 + lane] = make_float2(ox, oy);
    } else {
        __half2 p = __floats2half2_rn(ox, oy);
        ((__half2*)outH)[(size_t)node * 64 + lane] = p;
    }
}

extern "C" void kernel_launch(void* const* d_in, const int* in_sizes, int n_in,
                              void* d_out, int out_size, void* d_ws, size_t ws_size,
                              hipStream_t stream) {
    const float* x  = (const float*)d_in[0];
    const int*   ei = (const int*)d_in[1];
    const float* W1 = (const float*)d_in[2];
    const float* b1 = (const float*)d_in[3];
    const float* W2 = (const float*)d_in[4];
    const float* b2 = (const float*)d_in[5];
    const int N = in_sizes[0] / 128;
    const int E = in_sizes[1] / 2;
    const int NB = (N + BK - 1) / BK;       // 391 buckets

    char* w = (char*)d_ws;
    auto alloc = [&](size_t bytes) -> void* {
        void* p = (void*)w;
        w += (bytes + 255) & ~(size_t)255;
        return p;
    };
    int*      degi     = (int*)alloc((size_t)N * 4);
    float*    dinv     = (float*)alloc((size_t)N * 4);
    int*      excl     = (int*)alloc((size_t)N * 4);
    int*      partials = (int*)alloc(1024);
    int*      bcnt     = (int*)alloc((size_t)(NB + 1) * 4);
    int*      bstart   = (int*)alloc((size_t)(NB + 1) * 4);
    int*      gcur     = (int*)alloc((size_t)NB * 4);
    unsigned* ebuf     = (unsigned*)alloc((size_t)E * 4);
    int*      srcs     = (int*)alloc((size_t)E * 4);
    __half*   H        = (__half*)alloc((size_t)N * 128 * 2);
    __half*   Z        = (__half*)alloc((size_t)N * 128 * 2);

    const int* rowp = ei;
    const int* colp = ei + E;
    const int chunk = (E + NB - 1) / NB;
    const int nScanBlk = (N + 255) / 256;   // 196 <= 256

    {
        void* args[] = {
            (void*)&rowp, (void*)&colp, (void*)&bcnt, (void*)&bstart, (void*)&gcur,
            (void*)&ebuf, (void*)&srcs, (void*)&degi, (void*)&dinv,
            (void*)&excl, (void*)&partials,
            (void*)&N, (void*)&E, (void*)&NB, (void*)&chunk, (void*)&nScanBlk
        };
        hipLaunchCooperativeKernel((const void*)k_csr, dim3(NB), dim3(256),
                                   args, 0, stream);
    }

    k_gemm<float><<<(N + 63) / 64, 256, 0, stream>>>(x, W1, H, N);
    k_agg<<<(N + 3) / 4, 256, 0, stream>>>(H, srcs, excl, partials, degi, dinv, b1,
                                           nullptr, Z, N);
    k_gemm<__half><<<(N + 63) / 64, 256, 0, stream>>>(Z, W2, H, N);
    k_agg<<<(N + 3) / 4, 256, 0, stream>>>(H, srcs, excl, partials, degi, dinv, b2,
                                           (float*)d_out, nullptr, N);
}

// Round 8
// 186.932 us; speedup vs baseline: 2.5977x; 2.5977x over previous
//
#include <hip/hip_runtime.h>
#include <hip/hip_bf16.h>
#include <hip/hip_fp16.h>

// GCN 2-layer: z = relu(A(relu(A(xW1)+b1)W2)+b2), A = D^-1/2 (Adj+I) D^-1/2
// N=50000, E=800000, D=128. Output: float32.
// CSR via fixed-capacity bucket sort: memset + 2 kernels, no global node scan.

#define BK 128                      // nodes per bucket
#define CAP 4096                    // edge capacity per bucket (mean 2048 + 45 sigma)
#define PACK_ROWBITS 20             // row in bits [0,20), colLocal in [20,27)
#define NB_MAX 512

// scatter packed entries into fixed-cap bucket regions; per-block LDS hist,
// one global atomic reservation per (block,bucket).
__global__ __launch_bounds__(256) void k_bscatter(const int* __restrict__ row,
                                                  const int* __restrict__ col,
                                                  int* gcur, unsigned* ebuf,
                                                  int E, int nb, int chunk) {
    __shared__ int h[NB_MAX];
    __shared__ int base[NB_MAX];
    const int t = threadIdx.x;
    const int e0 = blockIdx.x * chunk;
    const int e1 = min(e0 + chunk, E);
    for (int i = t; i < nb; i += 256) h[i] = 0;
    __syncthreads();
    for (int e = e0 + t; e < e1; e += 256) atomicAdd(&h[col[e] >> 7], 1);
    __syncthreads();
    for (int i = t; i < nb; i += 256) {
        base[i] = h[i] ? atomicAdd(&gcur[i], h[i]) : 0;
        h[i] = 0;                                   // reuse as local cursor
    }
    __syncthreads();
    for (int e = e0 + t; e < e1; e += 256) {
        int c = col[e];
        int b = c >> 7;
        int loc = atomicAdd(&h[b], 1);
        ebuf[b * CAP + base[b] + loc] =
            (unsigned)row[e] | ((unsigned)(c & (BK - 1)) << PACK_ROWBITS);
    }
}

// per-bucket: node degrees -> dinv/degi/startv (LDS scan) -> CSR fill.
// Everything bucket-local; srcs kept in the same fixed-cap layout.
__global__ __launch_bounds__(256) void k_bnodefill(const unsigned* __restrict__ ebuf,
                                                   const int* __restrict__ gcur,
                                                   int* degi, float* dinv, int* startv,
                                                   int* srcs, int N) {
    __shared__ int h[BK];      // degree, then local cursor
    __shared__ int sc[BK];     // inclusive scan
    const int t = threadIdx.x, b = blockIdx.x;
    const int s = b * CAP;
    const int cnt = gcur[b];
    if (t < BK) h[t] = 0;
    __syncthreads();
    for (int i = t; i < cnt; i += 256)
        atomicAdd(&h[(ebuf[s + i] >> PACK_ROWBITS) & (BK - 1)], 1);
    __syncthreads();
    int deg = (t < BK) ? h[t] : 0;
    if (t < BK) sc[t] = deg;
    __syncthreads();
    for (int o = 1; o < BK; o <<= 1) {
        int x = (t < BK && t >= o) ? sc[t - o] : 0;
        __syncthreads();
        if (t < BK) sc[t] += x;
        __syncthreads();
    }
    int node = b * BK + t;
    if (t < BK) {
        int lexcl = sc[t] - deg;
        if (node < N) {
            degi[node]   = deg;
            dinv[node]   = rsqrtf((float)deg + 1.0f);   // +1 self loop
            startv[node] = s + lexcl;
        }
        h[t] = lexcl;                                   // local cursor base
    }
    __syncthreads();
    for (int i = t; i < cnt; i += 256) {
        unsigned u = ebuf[s + i];
        int c = (u >> PACK_ROWBITS) & (BK - 1);
        int loc = atomicAdd(&h[c], 1);
        srcs[s + loc] = (int)(u & ((1u << PACK_ROWBITS) - 1));
    }
}

// --- C[M,128] = A[M,128] @ W[128,128], f32 accumulate, fp16 output ---
template <typename TIN>
__global__ __launch_bounds__(256) void k_gemm(const TIN* __restrict__ A,
                                              const float* __restrict__ W,
                                              __half* __restrict__ C, int M) {
    __shared__ float Xl[128][68];
    const int t = threadIdx.x;
    const int row0 = blockIdx.x * 64;

    for (int c = t; c < 2048; c += 256) {
        int kq = c & 31, r = c >> 5;
        float4 v = make_float4(0.f, 0.f, 0.f, 0.f);
        int gr = row0 + r;
        if (gr < M) {
            if constexpr (sizeof(TIN) == 4) {
                v = ((const float4*)A)[gr * 32 + kq];
            } else {
                uint2 hp = ((const uint2*)A)[gr * 32 + kq];
                float2 a = __half22float2(*reinterpret_cast<__half2*>(&hp.x));
                float2 b = __half22float2(*reinterpret_cast<__half2*>(&hp.y));
                v = make_float4(a.x, a.y, b.x, b.y);
            }
        }
        Xl[4 * kq + 0][r] = v.x;
        Xl[4 * kq + 1][r] = v.y;
        Xl[4 * kq + 2][r] = v.z;
        Xl[4 * kq + 3][r] = v.w;
    }
    __syncthreads();

    const int cg = t & 31;
    const int rg = t >> 5;
    float acc[8][4];
#pragma unroll
    for (int i = 0; i < 8; i++)
#pragma unroll
        for (int j = 0; j < 4; j++) acc[i][j] = 0.f;

    const float4* Wv = (const float4*)W;
#pragma unroll 4
    for (int k = 0; k < 128; k++) {
        const float4 w  = Wv[(k << 5) + cg];
        const float4 xa = *(const float4*)(&Xl[k][rg << 3]);
        const float4 xb = *(const float4*)(&Xl[k][(rg << 3) + 4]);
        const float xs[8] = {xa.x, xa.y, xa.z, xa.w, xb.x, xb.y, xb.z, xb.w};
        const float ws4[4] = {w.x, w.y, w.z, w.w};
#pragma unroll
        for (int i = 0; i < 8; i++)
#pragma unroll
            for (int j = 0; j < 4; j++) acc[i][j] = fmaf(xs[i], ws4[j], acc[i][j]);
    }

#pragma unroll
    for (int i = 0; i < 8; i++) {
        int row = row0 + (rg << 3) + i;
        if (row < M) {
            __half2 p0 = __floats2half2_rn(acc[i][0], acc[i][1]);
            __half2 p1 = __floats2half2_rn(acc[i][2], acc[i][3]);
            uint2 pk;
            pk.x = *reinterpret_cast<unsigned*>(&p0);
            pk.y = *reinterpret_cast<unsigned*>(&p1);
            ((uint2*)C)[row * 32 + cg] = pk;
        }
    }
}

// --- aggregation: out = relu(di*(sum_j dj*H[j] + di*H[i]) + b), H fp16 ---
__global__ __launch_bounds__(256) void k_agg(const __half* __restrict__ H,
                                             const int* __restrict__ srcs,
                                             const int* __restrict__ startv,
                                             const int* __restrict__ degi,
                                             const float* __restrict__ dinv,
                                             const float* __restrict__ bias,
                                             float* __restrict__ outF,
                                             __half* __restrict__ outH, int n) {
    int wave = threadIdx.x >> 6, lane = threadIdx.x & 63;
    int node = blockIdx.x * 4 + wave;
    if (node >= n) return;
    int s0 = startv[node];
    int d = degi[node];
    float di = dinv[node];
    const __half2* Hv = (const __half2*)H;

    float2 hv = __half22float2(Hv[(size_t)node * 64 + lane]);
    float ax = di * hv.x, ay = di * hv.y;

    for (int k = 0; k < d; k += 64) {
        int take = d - k; if (take > 64) take = 64;
        int idx = (lane < take) ? srcs[s0 + k + lane] : 0;
        float djl = (lane < take) ? dinv[idx] : 0.f;
        int u = 0;
        for (; u + 8 <= take; u += 8) {
            int jj[8]; float dd[8]; float2 vv[8];
#pragma unroll
            for (int q = 0; q < 8; q++) {
                jj[q] = __shfl(idx, u + q);
                dd[q] = __shfl(djl, u + q);
            }
#pragma unroll
            for (int q = 0; q < 8; q++) vv[q] = __half22float2(Hv[(size_t)jj[q] * 64 + lane]);
#pragma unroll
            for (int q = 0; q < 8; q++) {
                ax = fmaf(dd[q], vv[q].x, ax);
                ay = fmaf(dd[q], vv[q].y, ay);
            }
        }
        for (; u < take; u++) {
            int j = __shfl(idx, u);
            float dj = __shfl(djl, u);
            float2 v = __half22float2(Hv[(size_t)j * 64 + lane]);
            ax = fmaf(dj, v.x, ax); ay = fmaf(dj, v.y, ay);
        }
    }
    float2 b2 = ((const float2*)bias)[lane];
    float ox = fmaxf(fmaf(di, ax, b2.x), 0.f);
    float oy = fmaxf(fmaf(di, ay, b2.y), 0.f);
    if (outF) {
        ((float2*)outF)[(size_t)node * 64 + lane] = make_float2(ox, oy);
    } else {
        __half2 p = __floats2half2_rn(ox, oy);
        ((__half2*)outH)[(size_t)node * 64 + lane] = p;
    }
}

extern "C" void kernel_launch(void* const* d_in, const int* in_sizes, int n_in,
                              void* d_out, int out_size, void* d_ws, size_t ws_size,
                              hipStream_t stream) {
    const float* x  = (const float*)d_in[0];
    const int*   ei = (const int*)d_in[1];
    const float* W1 = (const float*)d_in[2];
    const float* b1 = (const float*)d_in[3];
    const float* W2 = (const float*)d_in[4];
    const float* b2 = (const float*)d_in[5];
    const int N = in_sizes[0] / 128;
    const int E = in_sizes[1] / 2;
    const int NB = (N + BK - 1) / BK;       // 391 buckets

    char* w = (char*)d_ws;
    auto alloc = [&](size_t bytes) -> void* {
        void* p = (void*)w;
        w += (bytes + 255) & ~(size_t)255;
        return p;
    };
    int*      degi     = (int*)alloc((size_t)N * 4);
    float*    dinv     = (float*)alloc((size_t)N * 4);
    int*      startv   = (int*)alloc((size_t)N * 4);
    int*      gcur     = (int*)alloc((size_t)NB * 4);
    unsigned* ebuf     = (unsigned*)alloc((size_t)NB * CAP * 4);
    int*      srcs     = (int*)alloc((size_t)NB * CAP * 4);
    __half*   H        = (__half*)alloc((size_t)N * 128 * 2);
    __half*   Z        = (__half*)alloc((size_t)N * 128 * 2);

    const int* rowp = ei;
    const int* colp = ei + E;
    const int chunk = 8192;
    const int nScatter = (E + chunk - 1) / chunk;

    hipMemsetAsync(gcur, 0, (size_t)NB * 4, stream);
    k_bscatter<<<nScatter, 256, 0, stream>>>(rowp, colp, gcur, ebuf, E, NB, chunk);
    k_bnodefill<<<NB, 256, 0, stream>>>(ebuf, gcur, degi, dinv, startv, srcs, N);

    k_gemm<float><<<(N + 63) / 64, 256, 0, stream>>>(x, W1, H, N);
    k_agg<<<(N + 3) / 4, 256, 0, stream>>>(H, srcs, startv, degi, dinv, b1,
                                           nullptr, Z, N);
    k_gemm<__half><<<(N + 63) / 64, 256, 0, stream>>>(Z, W2, H, N);
    k_agg<<<(N + 3) / 4, 256, 0, stream>>>(H, srcs, startv, degi, dinv, b2,
                                           (float*)d_out, nullptr, N);
}

// Round 9
// 176.230 us; speedup vs baseline: 2.7554x; 1.0607x over previous
//
#include <hip/hip_runtime.h>
#include <hip/hip_bf16.h>
#include <hip/hip_fp16.h>

// GCN 2-layer: z = relu(A(relu(A(xW1)+b1)W2)+b2), A = D^-1/2 (Adj+I) D^-1/2
// N=50000, E=800000, D=128. Output: float32.
// CSR via fixed-capacity bucket sort: memset + 2 kernels, no global node scan.

#define BK 128                      // nodes per bucket
#define CAP 4096                    // edge capacity per bucket (mean 2048 + 45 sigma)
#define PACK_ROWBITS 20             // row in bits [0,20), colLocal in [20,27)
#define NB_MAX 512
#define CHUNK 2048                  // edges per scatter block (391 blocks: occupancy fix)

// scatter packed entries into fixed-cap bucket regions; per-block LDS hist,
// one global atomic reservation per (block,bucket). col cached in registers.
__global__ __launch_bounds__(256) void k_bscatter(const int* __restrict__ row,
                                                  const int* __restrict__ col,
                                                  int* gcur, unsigned* ebuf,
                                                  int E, int nb) {
    __shared__ int h[NB_MAX];
    __shared__ int base[NB_MAX];
    const int t = threadIdx.x;
    const int e0 = blockIdx.x * CHUNK;
    int cs[CHUNK / 256];
    for (int i = t; i < nb; i += 256) h[i] = 0;
    __syncthreads();
#pragma unroll
    for (int q = 0; q < CHUNK / 256; q++) {
        int e = e0 + q * 256 + t;
        cs[q] = (e < E) ? col[e] : -1;
        if (cs[q] >= 0) atomicAdd(&h[cs[q] >> 7], 1);
    }
    __syncthreads();
    for (int i = t; i < nb; i += 256) {
        base[i] = h[i] ? atomicAdd(&gcur[i], h[i]) : 0;
        h[i] = 0;                                   // reuse as local cursor
    }
    __syncthreads();
#pragma unroll
    for (int q = 0; q < CHUNK / 256; q++) {
        int e = e0 + q * 256 + t;
        if (cs[q] >= 0) {
            int c = cs[q];
            int b = c >> 7;
            int loc = atomicAdd(&h[b], 1);
            ebuf[b * CAP + base[b] + loc] =
                (unsigned)row[e] | ((unsigned)(c & (BK - 1)) << PACK_ROWBITS);
        }
    }
}

// per-bucket: node degrees -> dinv/degi/startv (LDS scan) -> CSR fill.
// Everything bucket-local; srcs kept in the same fixed-cap layout.
__global__ __launch_bounds__(256) void k_bnodefill(const unsigned* __restrict__ ebuf,
                                                   const int* __restrict__ gcur,
                                                   int* degi, float* dinv, int* startv,
                                                   int* srcs, int N) {
    __shared__ int h[BK];      // degree, then local cursor
    __shared__ int sc[BK];     // inclusive scan
    const int t = threadIdx.x, b = blockIdx.x;
    const int s = b * CAP;
    const int cnt = gcur[b];
    if (t < BK) h[t] = 0;
    __syncthreads();
    for (int i = t; i < cnt; i += 256)
        atomicAdd(&h[(ebuf[s + i] >> PACK_ROWBITS) & (BK - 1)], 1);
    __syncthreads();
    int deg = (t < BK) ? h[t] : 0;
    if (t < BK) sc[t] = deg;
    __syncthreads();
    for (int o = 1; o < BK; o <<= 1) {
        int x = (t < BK && t >= o) ? sc[t - o] : 0;
        __syncthreads();
        if (t < BK) sc[t] += x;
        __syncthreads();
    }
    int node = b * BK + t;
    if (t < BK) {
        int lexcl = sc[t] - deg;
        if (node < N) {
            degi[node]   = deg;
            dinv[node]   = rsqrtf((float)deg + 1.0f);   // +1 self loop
            startv[node] = s + lexcl;
        }
        h[t] = lexcl;                                   // local cursor base
    }
    __syncthreads();
    for (int i = t; i < cnt; i += 256) {
        unsigned u = ebuf[s + i];
        int c = (u >> PACK_ROWBITS) & (BK - 1);
        int loc = atomicAdd(&h[c], 1);
        srcs[s + loc] = (int)(u & ((1u << PACK_ROWBITS) - 1));
    }
}

// --- C[M,128] = A[M,128] @ W[128,128], f32 accumulate, fp16 output ---
template <typename TIN>
__global__ __launch_bounds__(256) void k_gemm(const TIN* __restrict__ A,
                                              const float* __restrict__ W,
                                              __half* __restrict__ C, int M) {
    __shared__ float Xl[128][68];
    const int t = threadIdx.x;
    const int row0 = blockIdx.x * 64;

    for (int c = t; c < 2048; c += 256) {
        int kq = c & 31, r = c >> 5;
        float4 v = make_float4(0.f, 0.f, 0.f, 0.f);
        int gr = row0 + r;
        if (gr < M) {
            if constexpr (sizeof(TIN) == 4) {
                v = ((const float4*)A)[gr * 32 + kq];
            } else {
                uint2 hp = ((const uint2*)A)[gr * 32 + kq];
                float2 a = __half22float2(*reinterpret_cast<__half2*>(&hp.x));
                float2 b = __half22float2(*reinterpret_cast<__half2*>(&hp.y));
                v = make_float4(a.x, a.y, b.x, b.y);
            }
        }
        Xl[4 * kq + 0][r] = v.x;
        Xl[4 * kq + 1][r] = v.y;
        Xl[4 * kq + 2][r] = v.z;
        Xl[4 * kq + 3][r] = v.w;
    }
    __syncthreads();

    const int cg = t & 31;
    const int rg = t >> 5;
    float acc[8][4];
#pragma unroll
    for (int i = 0; i < 8; i++)
#pragma unroll
        for (int j = 0; j < 4; j++) acc[i][j] = 0.f;

    const float4* Wv = (const float4*)W;
#pragma unroll 4
    for (int k = 0; k < 128; k++) {
        const float4 w  = Wv[(k << 5) + cg];
        const float4 xa = *(const float4*)(&Xl[k][rg << 3]);
        const float4 xb = *(const float4*)(&Xl[k][(rg << 3) + 4]);
        const float xs[8] = {xa.x, xa.y, xa.z, xa.w, xb.x, xb.y, xb.z, xb.w};
        const float ws4[4] = {w.x, w.y, w.z, w.w};
#pragma unroll
        for (int i = 0; i < 8; i++)
#pragma unroll
            for (int j = 0; j < 4; j++) acc[i][j] = fmaf(xs[i], ws4[j], acc[i][j]);
    }

#pragma unroll
    for (int i = 0; i < 8; i++) {
        int row = row0 + (rg << 3) + i;
        if (row < M) {
            __half2 p0 = __floats2half2_rn(acc[i][0], acc[i][1]);
            __half2 p1 = __floats2half2_rn(acc[i][2], acc[i][3]);
            uint2 pk;
            pk.x = *reinterpret_cast<unsigned*>(&p0);
            pk.y = *reinterpret_cast<unsigned*>(&p1);
            ((uint2*)C)[row * 32 + cg] = pk;
        }
    }
}

// --- aggregation: out = relu(di*(sum_j dj*H[j] + di*H[i]) + b), H fp16 ---
__global__ __launch_bounds__(256) void k_agg(const __half* __restrict__ H,
                                             const int* __restrict__ srcs,
                                             const int* __restrict__ startv,
                                             const int* __restrict__ degi,
                                             const float* __restrict__ dinv,
                                             const float* __restrict__ bias,
                                             float* __restrict__ outF,
                                             __half* __restrict__ outH, int n) {
    int wave = threadIdx.x >> 6, lane = threadIdx.x & 63;
    int node = blockIdx.x * 4 + wave;
    if (node >= n) return;
    int s0 = startv[node];
    int d = degi[node];
    float di = dinv[node];
    const __half2* Hv = (const __half2*)H;

    float2 hv = __half22float2(Hv[(size_t)node * 64 + lane]);
    float ax = di * hv.x, ay = di * hv.y;

    for (int k = 0; k < d; k += 64) {
        int take = d - k; if (take > 64) take = 64;
        int idx = (lane < take) ? srcs[s0 + k + lane] : 0;
        float djl = (lane < take) ? dinv[idx] : 0.f;
        int u = 0;
        for (; u + 8 <= take; u += 8) {
            int jj[8]; float dd[8]; float2 vv[8];
#pragma unroll
            for (int q = 0; q < 8; q++) {
                jj[q] = __shfl(idx, u + q);
                dd[q] = __shfl(djl, u + q);
            }
#pragma unroll
            for (int q = 0; q < 8; q++) vv[q] = __half22float2(Hv[(size_t)jj[q] * 64 + lane]);
#pragma unroll
            for (int q = 0; q < 8; q++) {
                ax = fmaf(dd[q], vv[q].x, ax);
                ay = fmaf(dd[q], vv[q].y, ay);
            }
        }
        for (; u < take; u++) {
            int j = __shfl(idx, u);
            float dj = __shfl(djl, u);
            float2 v = __half22float2(Hv[(size_t)j * 64 + lane]);
            ax = fmaf(dj, v.x, ax); ay = fmaf(dj, v.y, ay);
        }
    }
    float2 b2 = ((const float2*)bias)[lane];
    float ox = fmaxf(fmaf(di, ax, b2.x), 0.f);
    float oy = fmaxf(fmaf(di, ay, b2.y), 0.f);
    if (outF) {
        ((float2*)outF)[(size_t)node * 64 + lane] = make_float2(ox, oy);
    } else {
        __half2 p = __floats2half2_rn(ox, oy);
        ((__half2*)outH)[(size_t)node * 64 + lane] = p;
    }
}

extern "C" void kernel_launch(void* const* d_in, const int* in_sizes, int n_in,
                              void* d_out, int out_size, void* d_ws, size_t ws_size,
                              hipStream_t stream) {
    const float* x  = (const float*)d_in[0];
    const int*   ei = (const int*)d_in[1];
    const float* W1 = (const float*)d_in[2];
    const float* b1 = (const float*)d_in[3];
    const float* W2 = (const float*)d_in[4];
    const float* b2 = (const float*)d_in[5];
    const int N = in_sizes[0] / 128;
    const int E = in_sizes[1] / 2;
    const int NB = (N + BK - 1) / BK;       // 391 buckets

    char* w = (char*)d_ws;
    auto alloc = [&](size_t bytes) -> void* {
        void* p = (void*)w;
        w += (bytes + 255) & ~(size_t)255;
        return p;
    };
    int*      degi     = (int*)alloc((size_t)N * 4);
    float*    dinv     = (float*)alloc((size_t)N * 4);
    int*      startv   = (int*)alloc((size_t)N * 4);
    int*      gcur     = (int*)alloc((size_t)NB * 4);
    unsigned* ebuf     = (unsigned*)alloc((size_t)NB * CAP * 4);
    int*      srcs     = (int*)alloc((size_t)NB * CAP * 4);
    __half*   H        = (__half*)alloc((size_t)N * 128 * 2);
    __half*   Z        = (__half*)alloc((size_t)N * 128 * 2);

    const int* rowp = ei;
    const int* colp = ei + E;
    const int nScatter = (E + CHUNK - 1) / CHUNK;

    hipMemsetAsync(gcur, 0, (size_t)NB * 4, stream);
    k_bscatter<<<nScatter, 256, 0, stream>>>(rowp, colp, gcur, ebuf, E, NB);
    k_bnodefill<<<NB, 256, 0, stream>>>(ebuf, gcur, degi, dinv, startv, srcs, N);

    k_gemm<float><<<(N + 63) / 64, 256, 0, stream>>>(x, W1, H, N);
    k_agg<<<(N + 3) / 4, 256, 0, stream>>>(H, srcs, startv, degi, dinv, b1,
                                           nullptr, Z, N);
    k_gemm<__half><<<(N + 63) / 64, 256, 0, stream>>>(Z, W2, H, N);
    k_agg<<<(N + 3) / 4, 256, 0, stream>>>(H, srcs, startv, degi, dinv, b2,
                                           (float*)d_out, nullptr, N);
}

// Round 11
// 148.958 us; speedup vs baseline: 3.2599x; 1.1831x over previous
//
#include <hip/hip_runtime.h>
#include <hip/hip_bf16.h>
#include <hip/hip_fp16.h>

// GCN 2-layer: z = relu(A(relu(A(xW1)+b1)W2)+b2), A = D^-1/2 (Adj+I) D^-1/2
// N=50000, E=800000, D=128. Output: float32.
// CSR via fixed-capacity bucket sort; GEMM via v_mfma_f32_16x16x16_f16.

#define BK 128                      // nodes per bucket
#define CAP 4096                    // edge capacity per bucket (mean 2048 + 45 sigma)
#define PACK_ROWBITS 20             // row in bits [0,20), colLocal in [20,27)
#define NB_MAX 512
#define CHUNK 2048                  // edges per scatter block (391 blocks)

typedef __attribute__((ext_vector_type(4))) _Float16 f16x4;
typedef __attribute__((ext_vector_type(4))) float f32x4;

// scatter packed entries into fixed-cap bucket regions; per-block LDS hist,
// one global atomic reservation per (block,bucket). col cached in registers.
__global__ __launch_bounds__(256) void k_bscatter(const int* __restrict__ row,
                                                  const int* __restrict__ col,
                                                  int* gcur, unsigned* ebuf,
                                                  int E, int nb) {
    __shared__ int h[NB_MAX];
    __shared__ int base[NB_MAX];
    const int t = threadIdx.x;
    const int e0 = blockIdx.x * CHUNK;
    int cs[CHUNK / 256];
    for (int i = t; i < nb; i += 256) h[i] = 0;
    __syncthreads();
#pragma unroll
    for (int q = 0; q < CHUNK / 256; q++) {
        int e = e0 + q * 256 + t;
        cs[q] = (e < E) ? col[e] : -1;
        if (cs[q] >= 0) atomicAdd(&h[cs[q] >> 7], 1);
    }
    __syncthreads();
    for (int i = t; i < nb; i += 256) {
        base[i] = h[i] ? atomicAdd(&gcur[i], h[i]) : 0;
        h[i] = 0;                                   // reuse as local cursor
    }
    __syncthreads();
#pragma unroll
    for (int q = 0; q < CHUNK / 256; q++) {
        int e = e0 + q * 256 + t;
        if (cs[q] >= 0) {
            int c = cs[q];
            int b = c >> 7;
            int loc = atomicAdd(&h[b], 1);
            ebuf[b * CAP + base[b] + loc] =
                (unsigned)row[e] | ((unsigned)(c & (BK - 1)) << PACK_ROWBITS);
        }
    }
}

// per-bucket: node degrees -> dinv/degi/startv (LDS scan) -> CSR fill.
__global__ __launch_bounds__(256) void k_bnodefill(const unsigned* __restrict__ ebuf,
                                                   const int* __restrict__ gcur,
                                                   int* degi, float* dinv, int* startv,
                                                   int* srcs, int N) {
    __shared__ int h[BK];      // degree, then local cursor
    __shared__ int sc[BK];     // inclusive scan
    const int t = threadIdx.x, b = blockIdx.x;
    const int s = b * CAP;
    const int cnt = gcur[b];
    if (t < BK) h[t] = 0;
    __syncthreads();
    for (int i = t; i < cnt; i += 256)
        atomicAdd(&h[(ebuf[s + i] >> PACK_ROWBITS) & (BK - 1)], 1);
    __syncthreads();
    int deg = (t < BK) ? h[t] : 0;
    if (t < BK) sc[t] = deg;
    __syncthreads();
    for (int o = 1; o < BK; o <<= 1) {
        int x = (t < BK && t >= o) ? sc[t - o] : 0;
        __syncthreads();
        if (t < BK) sc[t] += x;
        __syncthreads();
    }
    int node = b * BK + t;
    if (t < BK) {
        int lexcl = sc[t] - deg;
        if (node < N) {
            degi[node]   = deg;
            dinv[node]   = rsqrtf((float)deg + 1.0f);   // +1 self loop
            startv[node] = s + lexcl;
        }
        h[t] = lexcl;                                   // local cursor base
    }
    __syncthreads();
    for (int i = t; i < cnt; i += 256) {
        unsigned u = ebuf[s + i];
        int c = (u >> PACK_ROWBITS) & (BK - 1);
        int loc = atomicAdd(&h[c], 1);
        srcs[s + loc] = (int)(u & ((1u << PACK_ROWBITS) - 1));
    }
}

// --- C[M,128] = A[M,128] @ W[128,128] via MFMA 16x16x16 f16, f32 accum ---
// Block 256 thr = 4 waves; wave computes a 16-row x 128-col strip.
// W staged transposed fp16 in LDS: Wt[n][k], pitch 136 (b64-minimum banking).
// Layouts (CDNA documented): a[i]=A[l%16][4*(l/16)+i], b[i]=B[4*(l/16)+i][l%16],
// d[i]=D[4*(l/16)+i][l%16]  (D layout HW-verified, learn_hip m89).
template <typename TIN>
__global__ __launch_bounds__(256) void k_gemm(const TIN* __restrict__ A,
                                              const float* __restrict__ W,
                                              __half* __restrict__ C, int M) {
    __shared__ _Float16 Wt[128][136];
    const int t = threadIdx.x;
    for (int idx = t; idx < 4096; idx += 256) {
        int k = idx >> 5, n4 = (idx & 31) << 2;
        float4 w4 = ((const float4*)W)[idx];        // W[k][n4..n4+3]
        Wt[n4 + 0][k] = (_Float16)w4.x;
        Wt[n4 + 1][k] = (_Float16)w4.y;
        Wt[n4 + 2][k] = (_Float16)w4.z;
        Wt[n4 + 3][k] = (_Float16)w4.w;
    }
    __syncthreads();

    const int wave = t >> 6, lane = t & 63;
    const int l16 = lane & 15, g = lane >> 4;
    const int rbase = blockIdx.x * 64 + wave * 16;
    int r = rbase + l16;
    if (r >= M) r = M - 1;                           // clamp (store is guarded)

    f32x4 acc[8];
#pragma unroll
    for (int ct = 0; ct < 8; ct++) acc[ct] = (f32x4){0.f, 0.f, 0.f, 0.f};

#pragma unroll
    for (int s = 0; s < 8; s++) {
        const int k0 = s * 16 + g * 4;
        f16x4 a;
        if constexpr (sizeof(TIN) == 4) {
            float4 a4 = *(const float4*)((const float*)A + (size_t)r * 128 + k0);
            a = (f16x4){(_Float16)a4.x, (_Float16)a4.y, (_Float16)a4.z, (_Float16)a4.w};
        } else {
            a = *(const f16x4*)((const _Float16*)A + (size_t)r * 128 + k0);
        }
#pragma unroll
        for (int ct = 0; ct < 8; ct++) {
            f16x4 b = *(const f16x4*)(&Wt[ct * 16 + l16][k0]);
            acc[ct] = __builtin_amdgcn_mfma_f32_16x16x16f16(a, b, acc[ct], 0, 0, 0);
        }
    }

#pragma unroll
    for (int ct = 0; ct < 8; ct++) {
#pragma unroll
        for (int i = 0; i < 4; i++) {
            int rr = rbase + g * 4 + i;
            if (rr < M)
                C[(size_t)rr * 128 + ct * 16 + l16] = __float2half(acc[ct][i]);
        }
    }
}

// --- aggregation: out = relu(di*(sum_j dj*H[j] + di*H[i]) + b), H fp16 ---
// one wave per node; padded 8-deep rounds (invalid slots: weight 0, self row).
__global__ __launch_bounds__(256) void k_agg(const __half* __restrict__ H,
                                             const int* __restrict__ srcs,
                                             const int* __restrict__ startv,
                                             const int* __restrict__ degi,
                                             const float* __restrict__ dinv,
                                             const float* __restrict__ bias,
                                             float* __restrict__ outF,
                                             __half* __restrict__ outH, int n) {
    int wave = threadIdx.x >> 6, lane = threadIdx.x & 63;
    int node = blockIdx.x * 4 + wave;
    if (node >= n) return;
    int s0 = startv[node];
    int d = degi[node];
    float di = dinv[node];
    const __half2* Hv = (const __half2*)H;

    float2 hv = __half22float2(Hv[(size_t)node * 64 + lane]);
    float ax = di * hv.x, ay = di * hv.y;

    for (int k = 0; k < d; k += 64) {
        int take = d - k; if (take > 64) take = 64;
        int idx = (lane < take) ? srcs[s0 + k + lane] : node;
        float djl = (lane < take) ? dinv[idx] : 0.f;
        for (int u = 0; u < take; u += 8) {
            int jj[8]; float dd[8]; float2 vv[8];
#pragma unroll
            for (int q = 0; q < 8; q++) {
                jj[q] = __shfl(idx, u + q);      // slots >= take: node, weight 0
                dd[q] = __shfl(djl, u + q);
            }
#pragma unroll
            for (int q = 0; q < 8; q++) vv[q] = __half22float2(Hv[(size_t)jj[q] * 64 + lane]);
#pragma unroll
            for (int q = 0; q < 8; q++) {
                ax = fmaf(dd[q], vv[q].x, ax);
                ay = fmaf(dd[q], vv[q].y, ay);
            }
        }
    }
    float2 b2 = ((const float2*)bias)[lane];
    float ox = fmaxf(fmaf(di, ax, b2.x), 0.f);
    float oy = fmaxf(fmaf(di, ay, b2.y), 0.f);
    if (outF) {
        ((float2*)outF)[(size_t)node * 64 + lane] = make_float2(ox, oy);
    } else {
        __half2 p = __floats2half2_rn(ox, oy);
        ((__half2*)outH)[(size_t)node * 64 + lane] = p;
    }
}

extern "C" void kernel_launch(void* const* d_in, const int* in_sizes, int n_in,
                              void* d_out, int out_size, void* d_ws, size_t ws_size,
                              hipStream_t stream) {
    const float* x  = (const float*)d_in[0];
    const int*   ei = (const int*)d_in[1];
    const float* W1 = (const float*)d_in[2];
    const float* b1 = (const float*)d_in[3];
    const float* W2 = (const float*)d_in[4];
    const float* b2 = (const float*)d_in[5];
    const int N = in_sizes[0] / 128;
    const int E = in_sizes[1] / 2;
    const int NB = (N + BK - 1) / BK;       // 391 buckets

    char* w = (char*)d_ws;
    auto alloc = [&](size_t bytes) -> void* {
        void* p = (void*)w;
        w += (bytes + 255) & ~(size_t)255;
        return p;
    };
    int*      degi     = (int*)alloc((size_t)N * 4);
    float*    dinv     = (float*)alloc((size_t)N * 4);
    int*      startv   = (int*)alloc((size_t)N * 4);
    int*      gcur     = (int*)alloc((size_t)NB * 4);
    unsigned* ebuf     = (unsigned*)alloc((size_t)NB * CAP * 4);
    int*      srcs     = (int*)alloc((size_t)NB * CAP * 4);
    __half*   H        = (__half*)alloc((size_t)N * 128 * 2);
    __half*   Z        = (__half*)alloc((size_t)N * 128 * 2);

    const int* rowp = ei;
    const int* colp = ei + E;
    const int nScatter = (E + CHUNK - 1) / CHUNK;

    (void)hipMemsetAsync(gcur, 0, (size_t)NB * 4, stream);
    k_bscatter<<<nScatter, 256, 0, stream>>>(rowp, colp, gcur, ebuf, E, NB);
    k_bnodefill<<<NB, 256, 0, stream>>>(ebuf, gcur, degi, dinv, startv, srcs, N);

    k_gemm<float><<<(N + 63) / 64, 256, 0, stream>>>(x, W1, H, N);
    k_agg<<<(N + 3) / 4, 256, 0, stream>>>(H, srcs, startv, degi, dinv, b1,
                                           nullptr, Z, N);
    k_gemm<__half><<<(N + 63) / 64, 256, 0, stream>>>(Z, W2, H, N);
    k_agg<<<(N + 3) / 4, 256, 0, stream>>>(H, srcs, startv, degi, dinv, b2,
                                           (float*)d_out, nullptr, N);
}

// Round 12
// 145.504 us; speedup vs baseline: 3.3373x; 1.0237x over previous
//
#include <hip/hip_runtime.h>
#include <hip/hip_bf16.h>
#include <hip/hip_fp16.h>

// GCN 2-layer: z = relu(A(relu(A(xW1)+b1)W2)+b2), A = D^-1/2 (Adj+I) D^-1/2
// N=50000, E=800000, D=128. Output: float32.
// CSR via fixed-capacity bucket sort; GEMM via MFMA 16x16x16 f16.
// Layer-1 GEMM fused with the edge scatter (independent stages, one dispatch).

#define BK 128                      // nodes per bucket
#define CAP 4096                    // edge capacity per bucket (mean 2048 + 45 sigma)
#define PACK_ROWBITS 20             // row in bits [0,20), colLocal in [20,27)
#define NB_MAX 512
#define CHUNK 2048                  // edges per scatter block (391 blocks)

typedef __attribute__((ext_vector_type(4))) _Float16 f16x4;
typedef __attribute__((ext_vector_type(4))) float f32x4;

// ---- fused: blocks [0,nScat) scatter edges; blocks [nScat,..) do layer-1 GEMM ----
__global__ __launch_bounds__(256) void k_fused(const int* __restrict__ row,
                                               const int* __restrict__ col,
                                               int* gcur, unsigned* ebuf,
                                               int E, int nb,
                                               const float* __restrict__ A,
                                               const float* __restrict__ W,
                                               __half* __restrict__ C, int M,
                                               int nScat) {
    __shared__ union {
        struct { int h[NB_MAX]; int base[NB_MAX]; } sc;
        _Float16 Wt[128][136];
    } u;
    const int t = threadIdx.x;

    if (blockIdx.x < nScat) {
        // ---------------- edge scatter ----------------
        const int e0 = blockIdx.x * CHUNK;
        int cs[CHUNK / 256];
        for (int i = t; i < nb; i += 256) u.sc.h[i] = 0;
        __syncthreads();
#pragma unroll
        for (int q = 0; q < CHUNK / 256; q++) {
            int e = e0 + q * 256 + t;
            cs[q] = (e < E) ? col[e] : -1;
            if (cs[q] >= 0) atomicAdd(&u.sc.h[cs[q] >> 7], 1);
        }
        __syncthreads();
        for (int i = t; i < nb; i += 256) {
            u.sc.base[i] = u.sc.h[i] ? atomicAdd(&gcur[i], u.sc.h[i]) : 0;
            u.sc.h[i] = 0;                          // reuse as local cursor
        }
        __syncthreads();
#pragma unroll
        for (int q = 0; q < CHUNK / 256; q++) {
            int e = e0 + q * 256 + t;
            if (cs[q] >= 0) {
                int c = cs[q];
                int b = c >> 7;
                int loc = atomicAdd(&u.sc.h[b], 1);
                ebuf[b * CAP + u.sc.base[b] + loc] =
                    (unsigned)row[e] | ((unsigned)(c & (BK - 1)) << PACK_ROWBITS);
            }
        }
    } else {
        // ---------------- layer-1 GEMM: C = f16(A @ W) ----------------
        const int bid = blockIdx.x - nScat;
        for (int idx = t; idx < 4096; idx += 256) {
            int k = idx >> 5, n4 = (idx & 31) << 2;
            float4 w4 = ((const float4*)W)[idx];    // W[k][n4..n4+3]
            u.Wt[n4 + 0][k] = (_Float16)w4.x;
            u.Wt[n4 + 1][k] = (_Float16)w4.y;
            u.Wt[n4 + 2][k] = (_Float16)w4.z;
            u.Wt[n4 + 3][k] = (_Float16)w4.w;
        }
        __syncthreads();

        const int wave = t >> 6, lane = t & 63;
        const int l16 = lane & 15, g = lane >> 4;
        const int rbase = bid * 64 + wave * 16;
        int r = rbase + l16;
        if (r >= M) r = M - 1;                      // clamp (store is guarded)

        f32x4 acc[8];
#pragma unroll
        for (int ct = 0; ct < 8; ct++) acc[ct] = (f32x4){0.f, 0.f, 0.f, 0.f};

#pragma unroll
        for (int s = 0; s < 8; s++) {
            const int k0 = s * 16 + g * 4;
            float4 a4 = *(const float4*)(A + (size_t)r * 128 + k0);
            f16x4 a = (f16x4){(_Float16)a4.x, (_Float16)a4.y,
                              (_Float16)a4.z, (_Float16)a4.w};
#pragma unroll
            for (int ct = 0; ct < 8; ct++) {
                f16x4 b = *(const f16x4*)(&u.Wt[ct * 16 + l16][k0]);
                acc[ct] = __builtin_amdgcn_mfma_f32_16x16x16f16(a, b, acc[ct], 0, 0, 0);
            }
        }

#pragma unroll
        for (int ct = 0; ct < 8; ct++) {
#pragma unroll
            for (int i = 0; i < 4; i++) {
                int rr = rbase + g * 4 + i;
                if (rr < M)
                    C[(size_t)rr * 128 + ct * 16 + l16] = __float2half(acc[ct][i]);
            }
        }
    }
}

// per-bucket: node degrees -> dinv/degi/startv (LDS scan) -> CSR fill.
__global__ __launch_bounds__(256) void k_bnodefill(const unsigned* __restrict__ ebuf,
                                                   const int* __restrict__ gcur,
                                                   int* degi, float* dinv, int* startv,
                                                   int* srcs, int N) {
    __shared__ int h[BK];      // degree, then local cursor
    __shared__ int sc[BK];     // inclusive scan
    const int t = threadIdx.x, b = blockIdx.x;
    const int s = b * CAP;
    const int cnt = gcur[b];
    if (t < BK) h[t] = 0;
    __syncthreads();
    for (int i = t; i < cnt; i += 256)
        atomicAdd(&h[(ebuf[s + i] >> PACK_ROWBITS) & (BK - 1)], 1);
    __syncthreads();
    int deg = (t < BK) ? h[t] : 0;
    if (t < BK) sc[t] = deg;
    __syncthreads();
    for (int o = 1; o < BK; o <<= 1) {
        int x = (t < BK && t >= o) ? sc[t - o] : 0;
        __syncthreads();
        if (t < BK) sc[t] += x;
        __syncthreads();
    }
    int node = b * BK + t;
    if (t < BK) {
        int lexcl = sc[t] - deg;
        if (node < N) {
            degi[node]   = deg;
            dinv[node]   = rsqrtf((float)deg + 1.0f);   // +1 self loop
            startv[node] = s + lexcl;
        }
        h[t] = lexcl;                                   // local cursor base
    }
    __syncthreads();
    for (int i = t; i < cnt; i += 256) {
        unsigned u = ebuf[s + i];
        int c = (u >> PACK_ROWBITS) & (BK - 1);
        int loc = atomicAdd(&h[c], 1);
        srcs[s + loc] = (int)(u & ((1u << PACK_ROWBITS) - 1));
    }
}

// --- layer-2 GEMM: C[M,128] = f16(A_f16[M,128] @ W[128,128]) ---
__global__ __launch_bounds__(256) void k_gemm2(const __half* __restrict__ A,
                                               const float* __restrict__ W,
                                               __half* __restrict__ C, int M) {
    __shared__ _Float16 Wt[128][136];
    const int t = threadIdx.x;
    for (int idx = t; idx < 4096; idx += 256) {
        int k = idx >> 5, n4 = (idx & 31) << 2;
        float4 w4 = ((const float4*)W)[idx];
        Wt[n4 + 0][k] = (_Float16)w4.x;
        Wt[n4 + 1][k] = (_Float16)w4.y;
        Wt[n4 + 2][k] = (_Float16)w4.z;
        Wt[n4 + 3][k] = (_Float16)w4.w;
    }
    __syncthreads();

    const int wave = t >> 6, lane = t & 63;
    const int l16 = lane & 15, g = lane >> 4;
    const int rbase = blockIdx.x * 64 + wave * 16;
    int r = rbase + l16;
    if (r >= M) r = M - 1;

    f32x4 acc[8];
#pragma unroll
    for (int ct = 0; ct < 8; ct++) acc[ct] = (f32x4){0.f, 0.f, 0.f, 0.f};

#pragma unroll
    for (int s = 0; s < 8; s++) {
        const int k0 = s * 16 + g * 4;
        f16x4 a = *(const f16x4*)((const _Float16*)A + (size_t)r * 128 + k0);
#pragma unroll
        for (int ct = 0; ct < 8; ct++) {
            f16x4 b = *(const f16x4*)(&Wt[ct * 16 + l16][k0]);
            acc[ct] = __builtin_amdgcn_mfma_f32_16x16x16f16(a, b, acc[ct], 0, 0, 0);
        }
    }

#pragma unroll
    for (int ct = 0; ct < 8; ct++) {
#pragma unroll
        for (int i = 0; i < 4; i++) {
            int rr = rbase + g * 4 + i;
            if (rr < M)
                C[(size_t)rr * 128 + ct * 16 + l16] = __float2half(acc[ct][i]);
        }
    }
}

// --- aggregation: out = relu(di*(sum_j dj*H[j] + di*H[i]) + b), H fp16 ---
// one wave per node; padded 16-deep rounds (invalid slots: weight 0, self row).
__global__ __launch_bounds__(256) void k_agg(const __half* __restrict__ H,
                                             const int* __restrict__ srcs,
                                             const int* __restrict__ startv,
                                             const int* __restrict__ degi,
                                             const float* __restrict__ dinv,
                                             const float* __restrict__ bias,
                                             float* __restrict__ outF,
                                             __half* __restrict__ outH, int n) {
    int wave = threadIdx.x >> 6, lane = threadIdx.x & 63;
    int node = blockIdx.x * 4 + wave;
    if (node >= n) return;
    int s0 = startv[node];
    int d = degi[node];
    float di = dinv[node];
    const __half2* Hv = (const __half2*)H;

    float2 hv = __half22float2(Hv[(size_t)node * 64 + lane]);
    float ax = di * hv.x, ay = di * hv.y;

    for (int k = 0; k < d; k += 64) {
        int take = d - k; if (take > 64) take = 64;
        int idx = (lane < take) ? srcs[s0 + k + lane] : node;
        float djl = (lane < take) ? dinv[idx] : 0.f;
        for (int u = 0; u < take; u += 16) {
            int jj[16]; float dd[16]; float2 vv[16];
#pragma unroll
            for (int q = 0; q < 16; q++) {
                jj[q] = __shfl(idx, u + q);      // slots >= take: node, weight 0
                dd[q] = __shfl(djl, u + q);
            }
#pragma unroll
            for (int q = 0; q < 16; q++) vv[q] = __half22float2(Hv[(size_t)jj[q] * 64 + lane]);
#pragma unroll
            for (int q = 0; q < 16; q++) {
                ax = fmaf(dd[q], vv[q].x, ax);
                ay = fmaf(dd[q], vv[q].y, ay);
            }
        }
    }
    float2 b2 = ((const float2*)bias)[lane];
    float ox = fmaxf(fmaf(di, ax, b2.x), 0.f);
    float oy = fmaxf(fmaf(di, ay, b2.y), 0.f);
    if (outF) {
        ((float2*)outF)[(size_t)node * 64 + lane] = make_float2(ox, oy);
    } else {
        __half2 p = __floats2half2_rn(ox, oy);
        ((__half2*)outH)[(size_t)node * 64 + lane] = p;
    }
}

extern "C" void kernel_launch(void* const* d_in, const int* in_sizes, int n_in,
                              void* d_out, int out_size, void* d_ws, size_t ws_size,
                              hipStream_t stream) {
    const float* x  = (const float*)d_in[0];
    const int*   ei = (const int*)d_in[1];
    const float* W1 = (const float*)d_in[2];
    const float* b1 = (const float*)d_in[3];
    const float* W2 = (const float*)d_in[4];
    const float* b2 = (const float*)d_in[5];
    const int N = in_sizes[0] / 128;
    const int E = in_sizes[1] / 2;
    const int NB = (N + BK - 1) / BK;       // 391 buckets

    char* w = (char*)d_ws;
    auto alloc = [&](size_t bytes) -> void* {
        void* p = (void*)w;
        w += (bytes + 255) & ~(size_t)255;
        return p;
    };
    int*      degi     = (int*)alloc((size_t)N * 4);
    float*    dinv     = (float*)alloc((size_t)N * 4);
    int*      startv   = (int*)alloc((size_t)N * 4);
    int*      gcur     = (int*)alloc((size_t)NB * 4);
    unsigned* ebuf     = (unsigned*)alloc((size_t)NB * CAP * 4);
    int*      srcs     = (int*)alloc((size_t)NB * CAP * 4);
    __half*   H        = (__half*)alloc((size_t)N * 128 * 2);
    __half*   Z        = (__half*)alloc((size_t)N * 128 * 2);

    const int* rowp = ei;
    const int* colp = ei + E;
    const int nScat = (E + CHUNK - 1) / CHUNK;       // 391
    const int nGemm = (N + 63) / 64;                 // 782

    (void)hipMemsetAsync(gcur, 0, (size_t)NB * 4, stream);
    k_fused<<<nScat + nGemm, 256, 0, stream>>>(rowp, colp, gcur, ebuf, E, NB,
                                               x, W1, H, N, nScat);
    k_bnodefill<<<NB, 256, 0, stream>>>(ebuf, gcur, degi, dinv, startv, srcs, N);

    k_agg<<<(N + 3) / 4, 256, 0, stream>>>(H, srcs, startv, degi, dinv, b1,
                                           nullptr, Z, N);
    k_gemm2<<<nGemm, 256, 0, stream>>>(Z, W2, H, N);
    k_agg<<<(N + 3) / 4, 256, 0, stream>>>(H, srcs, startv, degi, dinv, b2,
                                           (float*)d_out, nullptr, N);
}

// Round 13
// 144.276 us; speedup vs baseline: 3.3657x; 1.0085x over previous
//
#include <hip/hip_runtime.h>
#include <hip/hip_bf16.h>
#include <hip/hip_fp16.h>

// GCN 2-layer: z = relu(A(relu(A(xW1)+b1)W2)+b2), A = D^-1/2 (Adj+I) D^-1/2
// N=50000, E=800000, D=128. Output: float32.
// CSR via fixed-capacity bucket sort; GEMM via MFMA 16x16x16 f16.
// Layer-1 GEMM fused with the edge scatter (independent stages, one dispatch).

#define BK 128                      // nodes per bucket
#define CAP 4096                    // edge capacity per bucket (mean 2048 + 45 sigma)
#define PACK_ROWBITS 20             // row in bits [0,20), colLocal in [20,27)
#define NB_MAX 512
#define CHUNK 2048                  // edges per scatter block (391 blocks)

typedef __attribute__((ext_vector_type(4))) _Float16 f16x4;
typedef __attribute__((ext_vector_type(4))) float f32x4;

// ---- fused: blocks [0,nScat) scatter edges; blocks [nScat,..) do layer-1 GEMM ----
__global__ __launch_bounds__(256) void k_fused(const int* __restrict__ row,
                                               const int* __restrict__ col,
                                               int* gcur, unsigned* ebuf,
                                               int E, int nb,
                                               const float* __restrict__ A,
                                               const float* __restrict__ W,
                                               __half* __restrict__ C, int M,
                                               int nScat) {
    __shared__ union {
        struct { int h[NB_MAX]; int base[NB_MAX]; } sc;
        _Float16 Wt[128][136];
    } u;
    const int t = threadIdx.x;

    if (blockIdx.x < nScat) {
        // ---------------- edge scatter ----------------
        const int e0 = blockIdx.x * CHUNK;
        int cs[CHUNK / 256];
        for (int i = t; i < nb; i += 256) u.sc.h[i] = 0;
        __syncthreads();
#pragma unroll
        for (int q = 0; q < CHUNK / 256; q++) {
            int e = e0 + q * 256 + t;
            cs[q] = (e < E) ? col[e] : -1;
            if (cs[q] >= 0) atomicAdd(&u.sc.h[cs[q] >> 7], 1);
        }
        __syncthreads();
        for (int i = t; i < nb; i += 256) {
            u.sc.base[i] = u.sc.h[i] ? atomicAdd(&gcur[i], u.sc.h[i]) : 0;
            u.sc.h[i] = 0;                          // reuse as local cursor
        }
        __syncthreads();
#pragma unroll
        for (int q = 0; q < CHUNK / 256; q++) {
            int e = e0 + q * 256 + t;
            if (cs[q] >= 0) {
                int c = cs[q];
                int b = c >> 7;
                int loc = atomicAdd(&u.sc.h[b], 1);
                ebuf[b * CAP + u.sc.base[b] + loc] =
                    (unsigned)row[e] | ((unsigned)(c & (BK - 1)) << PACK_ROWBITS);
            }
        }
    } else {
        // ---------------- layer-1 GEMM: C = f16(A @ W) ----------------
        const int bid = blockIdx.x - nScat;
        for (int idx = t; idx < 4096; idx += 256) {
            int k = idx >> 5, n4 = (idx & 31) << 2;
            float4 w4 = ((const float4*)W)[idx];    // W[k][n4..n4+3]
            u.Wt[n4 + 0][k] = (_Float16)w4.x;
            u.Wt[n4 + 1][k] = (_Float16)w4.y;
            u.Wt[n4 + 2][k] = (_Float16)w4.z;
            u.Wt[n4 + 3][k] = (_Float16)w4.w;
        }
        __syncthreads();

        const int wave = t >> 6, lane = t & 63;
        const int l16 = lane & 15, g = lane >> 4;
        const int rbase = bid * 64 + wave * 16;
        int r = rbase + l16;
        if (r >= M) r = M - 1;                      // clamp (store is guarded)

        f32x4 acc[8];
#pragma unroll
        for (int ct = 0; ct < 8; ct++) acc[ct] = (f32x4){0.f, 0.f, 0.f, 0.f};

#pragma unroll
        for (int s = 0; s < 8; s++) {
            const int k0 = s * 16 + g * 4;
            float4 a4 = *(const float4*)(A + (size_t)r * 128 + k0);
            f16x4 a = (f16x4){(_Float16)a4.x, (_Float16)a4.y,
                              (_Float16)a4.z, (_Float16)a4.w};
#pragma unroll
            for (int ct = 0; ct < 8; ct++) {
                f16x4 b = *(const f16x4*)(&u.Wt[ct * 16 + l16][k0]);
                acc[ct] = __builtin_amdgcn_mfma_f32_16x16x16f16(a, b, acc[ct], 0, 0, 0);
            }
        }

#pragma unroll
        for (int ct = 0; ct < 8; ct++) {
#pragma unroll
            for (int i = 0; i < 4; i++) {
                int rr = rbase + g * 4 + i;
                if (rr < M)
                    C[(size_t)rr * 128 + ct * 16 + l16] = __float2half(acc[ct][i]);
            }
        }
    }
}

// per-bucket: node degrees -> dinv/degi/startv (LDS scan) -> CSR fill.
// 1024 threads (16 waves): the 2 ebuf passes are latency-bound at 391 blocks.
__global__ __launch_bounds__(1024) void k_bnodefill(const unsigned* __restrict__ ebuf,
                                                    const int* __restrict__ gcur,
                                                    int* degi, float* dinv, int* startv,
                                                    int* srcs, int N) {
    __shared__ int h[BK];      // degree, then local cursor
    __shared__ int sc[BK];     // inclusive scan
    const int t = threadIdx.x, b = blockIdx.x;
    const int s = b * CAP;
    const int cnt = gcur[b];
    if (t < BK) h[t] = 0;
    __syncthreads();
    for (int i = t; i < cnt; i += 1024)
        atomicAdd(&h[(ebuf[s + i] >> PACK_ROWBITS) & (BK - 1)], 1);
    __syncthreads();
    int deg = (t < BK) ? h[t] : 0;
    if (t < BK) sc[t] = deg;
    __syncthreads();
    for (int o = 1; o < BK; o <<= 1) {
        int x = (t < BK && t >= o) ? sc[t - o] : 0;
        __syncthreads();
        if (t < BK) sc[t] += x;
        __syncthreads();
    }
    int node = b * BK + t;
    if (t < BK) {
        int lexcl = sc[t] - deg;
        if (node < N) {
            degi[node]   = deg;
            dinv[node]   = rsqrtf((float)deg + 1.0f);   // +1 self loop
            startv[node] = s + lexcl;
        }
        h[t] = lexcl;                                   // local cursor base
    }
    __syncthreads();
    for (int i = t; i < cnt; i += 1024) {
        unsigned u = ebuf[s + i];
        int c = (u >> PACK_ROWBITS) & (BK - 1);
        int loc = atomicAdd(&h[c], 1);
        srcs[s + loc] = (int)(u & ((1u << PACK_ROWBITS) - 1));
    }
}

// --- layer-2 GEMM: C[M,128] = f16(A_f16[M,128] @ W[128,128]) ---
__global__ __launch_bounds__(256) void k_gemm2(const __half* __restrict__ A,
                                               const float* __restrict__ W,
                                               __half* __restrict__ C, int M) {
    __shared__ _Float16 Wt[128][136];
    const int t = threadIdx.x;
    for (int idx = t; idx < 4096; idx += 256) {
        int k = idx >> 5, n4 = (idx & 31) << 2;
        float4 w4 = ((const float4*)W)[idx];
        Wt[n4 + 0][k] = (_Float16)w4.x;
        Wt[n4 + 1][k] = (_Float16)w4.y;
        Wt[n4 + 2][k] = (_Float16)w4.z;
        Wt[n4 + 3][k] = (_Float16)w4.w;
    }
    __syncthreads();

    const int wave = t >> 6, lane = t & 63;
    const int l16 = lane & 15, g = lane >> 4;
    const int rbase = blockIdx.x * 64 + wave * 16;
    int r = rbase + l16;
    if (r >= M) r = M - 1;

    f32x4 acc[8];
#pragma unroll
    for (int ct = 0; ct < 8; ct++) acc[ct] = (f32x4){0.f, 0.f, 0.f, 0.f};

#pragma unroll
    for (int s = 0; s < 8; s++) {
        const int k0 = s * 16 + g * 4;
        f16x4 a = *(const f16x4*)((const _Float16*)A + (size_t)r * 128 + k0);
#pragma unroll
        for (int ct = 0; ct < 8; ct++) {
            f16x4 b = *(const f16x4*)(&Wt[ct * 16 + l16][k0]);
            acc[ct] = __builtin_amdgcn_mfma_f32_16x16x16f16(a, b, acc[ct], 0, 0, 0);
        }
    }

#pragma unroll
    for (int ct = 0; ct < 8; ct++) {
#pragma unroll
        for (int i = 0; i < 4; i++) {
            int rr = rbase + g * 4 + i;
            if (rr < M)
                C[(size_t)rr * 128 + ct * 16 + l16] = __float2half(acc[ct][i]);
        }
    }
}

// --- aggregation: out = relu(di*(sum_j dj*H[j] + di*H[i]) + b), H fp16 ---
// one wave per node; padded 16-deep rounds. Rows staged as RAW __half2
// (1 VGPR each, not float2's 2) and the dinv shuffles folded into the FMA
// phase -> target <=64 VGPR for 8 waves/SIMD occupancy.
__global__ __launch_bounds__(256) void k_agg(const __half* __restrict__ H,
                                             const int* __restrict__ srcs,
                                             const int* __restrict__ startv,
                                             const int* __restrict__ degi,
                                             const float* __restrict__ dinv,
                                             const float* __restrict__ bias,
                                             float* __restrict__ outF,
                                             __half* __restrict__ outH, int n) {
    int wave = threadIdx.x >> 6, lane = threadIdx.x & 63;
    int node = blockIdx.x * 4 + wave;
    if (node >= n) return;
    int s0 = startv[node];
    int d = degi[node];
    float di = dinv[node];
    const __half2* Hv = (const __half2*)H;

    float2 hv = __half22float2(Hv[(size_t)node * 64 + lane]);
    float ax = di * hv.x, ay = di * hv.y;

    for (int k = 0; k < d; k += 64) {
        int take = d - k; if (take > 64) take = 64;
        int idx = (lane < take) ? srcs[s0 + k + lane] : node;
        float djl = (lane < take) ? dinv[idx] : 0.f;
        for (int u = 0; u < take; u += 16) {
            int jj[16]; __half2 hh[16];
#pragma unroll
            for (int q = 0; q < 16; q++)
                jj[q] = __shfl(idx, u + q);      // slots >= take: node, weight 0
#pragma unroll
            for (int q = 0; q < 16; q++)
                hh[q] = Hv[(size_t)jj[q] * 64 + lane];
#pragma unroll
            for (int q = 0; q < 16; q++) {
                float dj = __shfl(djl, u + q);
                float2 v = __half22float2(hh[q]);
                ax = fmaf(dj, v.x, ax);
                ay = fmaf(dj, v.y, ay);
            }
        }
    }
    float2 b2 = ((const float2*)bias)[lane];
    float ox = fmaxf(fmaf(di, ax, b2.x), 0.f);
    float oy = fmaxf(fmaf(di, ay, b2.y), 0.f);
    if (outF) {
        ((float2*)outF)[(size_t)node * 64 + lane] = make_float2(ox, oy);
    } else {
        __half2 p = __floats2half2_rn(ox, oy);
        ((__half2*)outH)[(size_t)node * 64 + lane] = p;
    }
}

extern "C" void kernel_launch(void* const* d_in, const int* in_sizes, int n_in,
                              void* d_out, int out_size, void* d_ws, size_t ws_size,
                              hipStream_t stream) {
    const float* x  = (const float*)d_in[0];
    const int*   ei = (const int*)d_in[1];
    const float* W1 = (const float*)d_in[2];
    const float* b1 = (const float*)d_in[3];
    const float* W2 = (const float*)d_in[4];
    const float* b2 = (const float*)d_in[5];
    const int N = in_sizes[0] / 128;
    const int E = in_sizes[1] / 2;
    const int NB = (N + BK - 1) / BK;       // 391 buckets

    char* w = (char*)d_ws;
    auto alloc = [&](size_t bytes) -> void* {
        void* p = (void*)w;
        w += (bytes + 255) & ~(size_t)255;
        return p;
    };
    int*      degi     = (int*)alloc((size_t)N * 4);
    float*    dinv     = (float*)alloc((size_t)N * 4);
    int*      startv   = (int*)alloc((size_t)N * 4);
    int*      gcur     = (int*)alloc((size_t)NB * 4);
    unsigned* ebuf     = (unsigned*)alloc((size_t)NB * CAP * 4);
    int*      srcs     = (int*)alloc((size_t)NB * CAP * 4);
    __half*   H        = (__half*)alloc((size_t)N * 128 * 2);
    __half*   Z        = (__half*)alloc((size_t)N * 128 * 2);

    const int* rowp = ei;
    const int* colp = ei + E;
    const int nScat = (E + CHUNK - 1) / CHUNK;       // 391
    const int nGemm = (N + 63) / 64;                 // 782

    (void)hipMemsetAsync(gcur, 0, (size_t)NB * 4, stream);
    k_fused<<<nScat + nGemm, 256, 0, stream>>>(rowp, colp, gcur, ebuf, E, NB,
                                               x, W1, H, N, nScat);
    k_bnodefill<<<NB, 1024, 0, stream>>>(ebuf, gcur, degi, dinv, startv, srcs, N);

    k_agg<<<(N + 3) / 4, 256, 0, stream>>>(H, srcs, startv, degi, dinv, b1,
                                           nullptr, Z, N);
    k_gemm2<<<nGemm, 256, 0, stream>>>(Z, W2, H, N);
    k_agg<<<(N + 3) / 4, 256, 0, stream>>>(H, srcs, startv, degi, dinv, b2,
                                           (float*)d_out, nullptr, N);
}